// Round 10
// baseline (882.527 us; speedup 1.0000x reference)
//
#include <hip/hip_runtime.h>
#include <stdint.h>

#define SEQ 8192
#define CS 64                       // chunk length == block row tile
#define NCH 128                     // chunks per sequence
#define NBLK 4096                   // 32 batches * 128 chunks

typedef float f32x4 __attribute__((ext_vector_type(4)));
typedef short short8 __attribute__((ext_vector_type(8)));
typedef unsigned short u16;
typedef u16 ushort8 __attribute__((ext_vector_type(8)));
typedef u16 ushort4v __attribute__((ext_vector_type(4)));
typedef unsigned long long u64;

__device__ __forceinline__ u16 f2bf(float f) {
  uint32_t u = __float_as_uint(f);
  u += 0x7fffu + ((u >> 16) & 1u);   // round-to-nearest-even
  return (u16)(u >> 16);
}

// ---------- emb f32 -> bf16 table + zero sync area (one-time per launch) ----------
__global__ void embq_kernel(const float* __restrict__ emb, u16* __restrict__ embq,
                            int* __restrict__ syncA) {
  int g = blockIdx.x * 256 + threadIdx.x;
  if (g < 1 + NBLK) syncA[g] = 0;          // ticket + flags
  int i = g * 4;                            // 8,192,000 elements exactly
  float4 v = *(const float4*)(emb + i);
  ushort4v p;
  p[0] = f2bf(v.x); p[1] = f2bf(v.y); p[2] = f2bf(v.z); p[3] = f2bf(v.w);
  *(ushort4v*)(embq + i) = p;
}

// ---------- weight preprocess: f32 [l][k][d] -> bf16 swizzled 8KB tiles ----------
// WtS: 64 tiles of 8192 BYTES, tile index (mat*4 + dh)*4 + kt, in-tile [64 dloc][64 kl],
// byte = (dloc*128 + kl*2) ^ ((dloc&7)<<4).  mat: 0=Wz l0,1=Wz l1,2=Wh l0,3=Wh l1
__global__ void wt_kernel(const float* __restrict__ Wz, const float* __restrict__ Wh,
                          u16* __restrict__ WtS) {
  int idx = blockIdx.x * 256 + threadIdx.x;   // 4*65536
  int d = idx & 255;
  int k = (idx >> 8) & 255;
  int m = idx >> 16;
  const float* src = (m < 2 ? Wz : Wh) + (size_t)(m & 1) * 65536;
  float v = src[k * 256 + d];
  int dh = d >> 6, dloc = d & 63, kt = k >> 6, kl = k & 63;
  size_t tile = ((size_t)(m * 4 + dh) * 4 + kt) * 8192;   // BYTES
  size_t byte = (size_t)((dloc * 128 + kl * 2) ^ ((dloc & 7) << 4));
  *(u16*)((char*)WtS + tile + byte) = f2bf(v);
}

// ---- 4-kt MFMA core: A from LDS (swizzled subtiles), B direct from global (L2-hot) ----
// wave w owns d in [64w, 64w+64): dh = w. No barriers inside.
__device__ __forceinline__ void gemm_core(int lsel, const char* WtSb,
    const u16* As, int w, int l15, int lg,
    f32x4 (&accz)[4][4], f32x4 (&acch)[4][4])
{
  const char* basez = WtSb + (size_t)((lsel * 4 + w) * 4) * 8192;
  const char* baseh = WtSb + (size_t)(((2 + lsel) * 4 + w) * 4) * 8192;
  const int xm = (l15 & 7) << 4;
  for (int kt = 0; kt < 4; kt++) {
    #pragma unroll
    for (int ks = 0; ks < 2; ks++) {
      short8 fa[4];
      #pragma unroll
      for (int mi = 0; mi < 4; mi++)
        fa[mi] = *(const short8*)((const char*)As + kt * 8192 +
                   (((mi * 16 + l15) * 128 + ks * 64 + lg * 16) ^ xm));
      #pragma unroll
      for (int ni = 0; ni < 4; ni++) {
        const int off = (((ni * 16 + l15) * 128 + ks * 64 + lg * 16) ^ xm);
        short8 fbz = *(const short8*)(basez + kt * 8192 + off);
        short8 fbh = *(const short8*)(baseh + kt * 8192 + off);
        #pragma unroll
        for (int mi = 0; mi < 4; mi++) {
          accz[mi][ni] = __builtin_amdgcn_mfma_f32_16x16x32_bf16(fa[mi], fbz, accz[mi][ni], 0, 0, 0);
          acch[mi][ni] = __builtin_amdgcn_mfma_f32_16x16x32_bf16(fa[mi], fbh, acch[mi][ni], 0, 0, 0);
        }
      }
    }
  }
}

// ---------- fused kernel: both layers + scan via decoupled lookback ----------
// Block: 256 threads (4 waves), 64 rows (one chunk) x 256 d, K=256.
__global__ __launch_bounds__(256, 2)
void fused_kernel(const int* __restrict__ x, const u16* __restrict__ embq,
                  const u16* __restrict__ WtS,
                  const float* __restrict__ bz0, const float* __restrict__ bh0,
                  const float* __restrict__ bz1, const float* __restrict__ bh1,
                  u64* __restrict__ Loc0, float2* __restrict__ Loc1,
                  int* __restrict__ flag0, int* __restrict__ ticket)
{
  __shared__ __align__(16) u16 As[16384];      // 32KB: 4 subtiles [64t][64k] swizzled
  __shared__ __align__(16) float2 SegT[4096];  // 32KB: [16 seg][256 d]
  __shared__ float hin[256];
  __shared__ int vb_sh;

  const int tid = threadIdx.x;
  const int lane = tid & 63;
  const int w = tid >> 6;                      // 0..3, owns d in [64w, 64w+64)
  const int l15 = lane & 15, lg = lane >> 4;
  const char* WtSb = (const char*)WtS;

  if (tid == 0) vb_sh = atomicAdd(ticket, 1);
  __syncthreads();
  const int vb = vb_sh;
  const int b = vb & 31;
  const int c = vb >> 5;                       // 0..127, ascending in ticket order
  const int cb = b * NCH + c;

  // ---- A gather: 64 rows x 256 k, thread = (row sm, k-quarter kq) ----
  {
    const int sm = tid >> 2, kq = tid & 3;
    const int tok = x[b * SEQ + c * CS + sm];
    const u16* src = embq + (size_t)tok * 256 + kq * 64;
    char* sub = (char*)As + kq * 8192;
    const int swz = (sm & 7) << 4;
    #pragma unroll
    for (int j = 0; j < 8; j++) {
      ushort8 p = *(const ushort8*)(src + j * 8);
      *(ushort8*)(sub + ((sm * 128 + j * 16) ^ swz)) = p;
    }
  }

  f32x4 accz[4][4], acch[4][4];
  #pragma unroll
  for (int i = 0; i < 4; i++)
    #pragma unroll
    for (int j = 0; j < 4; j++) {
      f32x4 zz = {0.f, 0.f, 0.f, 0.f};
      accz[i][j] = zz; acch[i][j] = zz;
    }

  __syncthreads();                             // S1: As ready
  gemm_core(0, WtSb, As, w, l15, lg, accz, acch);

  // ---- layer-0 gates + per-segment (A,B) -> SegT ----
  #pragma unroll
  for (int ni = 0; ni < 4; ni++) {
    const int d = w * 64 + ni * 16 + l15;
    const float bzv = bz0[d];
    const float bhv = bh0[d];
    #pragma unroll
    for (int mi = 0; mi < 4; mi++) {
      float A = 1.f, B = 0.f;
      #pragma unroll
      for (int r = 0; r < 4; r++) {
        float zl = accz[mi][ni][r] + bzv;
        float zg = 1.f / (1.f + __expf(-zl));
        float ht = acch[mi][ni][r] + bhv;
        float a = 1.f - zg, bb = zg * ht;
        accz[mi][ni][r] = a;                   // keep a,b for h-rebuild
        acch[mi][ni][r] = bb;
        B = B * a + bb;
        A *= a;
      }
      SegT[(mi * 4 + lg) * 256 + d] = make_float2(A, B);   // seg = t/4
    }
  }
  __syncthreads();                             // S2: SegT complete

  // ---- exclusive prefix over 16 segs (thread owns d=tid) + publish local ----
  {
    float PA = 1.f, PB = 0.f;
    #pragma unroll
    for (int s = 0; s < 16; s++) {
      float2 v = SegT[s * 256 + tid];
      SegT[s * 256 + tid] = make_float2(PA, PB);
      PB = v.x * PB + v.y;
      PA = v.x * PA;
    }
    u64 pv = (u64)__float_as_uint(PA) | ((u64)__float_as_uint(PB) << 32);
    __hip_atomic_store(&Loc0[(size_t)cb * 256 + tid], pv, __ATOMIC_RELAXED, __HIP_MEMORY_SCOPE_AGENT);
    __threadfence();
  }
  __syncthreads();                             // S3: publishes done
  if (tid == 0)
    __hip_atomic_store(&flag0[cb], 1, __ATOMIC_RELEASE, __HIP_MEMORY_SCOPE_AGENT);
  if (w == 0 && c > 0) {
    const int fb = b * NCH;
    while (true) {
      int ok1 = (lane < c) ? __hip_atomic_load(&flag0[fb + lane],
                  __ATOMIC_RELAXED, __HIP_MEMORY_SCOPE_AGENT) : 1;
      int ok2 = (lane + 64 < c) ? __hip_atomic_load(&flag0[fb + lane + 64],
                  __ATOMIC_RELAXED, __HIP_MEMORY_SCOPE_AGENT) : 1;
      if (__all(ok1 != 0 && ok2 != 0)) break;
      __builtin_amdgcn_s_sleep(8);
    }
  }
  __syncthreads();                             // S4: predecessors visible

  // ---- lookback compose (thread owns d=tid), j ascending ----
  {
    float H = 0.f;
    for (int j0 = 0; j0 < c; j0 += 8) {
      u64 v[8];
      #pragma unroll
      for (int k = 0; k < 8; k++)
        if (j0 + k < c)
          v[k] = __hip_atomic_load(&Loc0[(size_t)(b * NCH + j0 + k) * 256 + tid],
                   __ATOMIC_RELAXED, __HIP_MEMORY_SCOPE_AGENT);
      #pragma unroll
      for (int k = 0; k < 8; k++)
        if (j0 + k < c) {
          float A = __uint_as_float((uint32_t)v[k]);
          float B = __uint_as_float((uint32_t)(v[k] >> 32));
          H = A * H + B;
        }
    }
    hin[tid] = H;
  }
  __syncthreads();                             // S5: hin ready

  // ---- rebuild h1 tile (reads SegT exclusive + hin + a,b regs) into As ----
  #pragma unroll
  for (int ni = 0; ni < 4; ni++) {
    const int d = w * 64 + ni * 16 + l15;
    char* sub = (char*)As + w * 8192;          // d>>6 == w
    const int kl2 = (ni * 16 + l15) * 2;
    const float h0 = hin[d];
    #pragma unroll
    for (int mi = 0; mi < 4; mi++) {
      float2 e = SegT[(mi * 4 + lg) * 256 + d];
      float h = e.x * h0 + e.y;
      #pragma unroll
      for (int r = 0; r < 4; r++) {
        h = accz[mi][ni][r] * h + acch[mi][ni][r];
        const int t = mi * 16 + lg * 4 + r;
        *(u16*)(sub + ((t * 128 + kl2) ^ ((t & 7) << 4))) = f2bf(h);
      }
    }
  }

  #pragma unroll
  for (int i = 0; i < 4; i++)
    #pragma unroll
    for (int j = 0; j < 4; j++) {
      f32x4 zz = {0.f, 0.f, 0.f, 0.f};
      accz[i][j] = zz; acch[i][j] = zz;
    }

  __syncthreads();                             // S6: h-tile ready, SegT reads done
  gemm_core(1, WtSb, As, w, l15, lg, accz, acch);

  // ---- layer-1 gates -> SegT ----
  #pragma unroll
  for (int ni = 0; ni < 4; ni++) {
    const int d = w * 64 + ni * 16 + l15;
    const float bzv = bz1[d];
    const float bhv = bh1[d];
    #pragma unroll
    for (int mi = 0; mi < 4; mi++) {
      float A = 1.f, B = 0.f;
      #pragma unroll
      for (int r = 0; r < 4; r++) {
        float zl = accz[mi][ni][r] + bzv;
        float zg = 1.f / (1.f + __expf(-zl));
        float ht = acch[mi][ni][r] + bhv;
        float a = 1.f - zg, bb = zg * ht;
        B = B * a + bb;
        A *= a;
      }
      SegT[(mi * 4 + lg) * 256 + d] = make_float2(A, B);
    }
  }
  __syncthreads();                             // S7: SegT complete
  {
    float PA = 1.f, PB = 0.f;
    #pragma unroll
    for (int s = 0; s < 16; s++) {
      float2 v = SegT[s * 256 + tid];
      PB = v.x * PB + v.y;
      PA = v.x * PA;
    }
    Loc1[(size_t)cb * 256 + tid] = make_float2(PA, PB);
  }
}

// ---------- layer-1 final: serial over chunk locals -> hlast ----------
__global__ void scan2_l1(const float2* __restrict__ Loc1, float* __restrict__ hlast) {
  const int g = blockIdx.x * 256 + threadIdx.x;   // 8192 = 32 b * 256 d
  const int b = g >> 8, d = g & 255;
  float h = 0.f;
  for (int c = 0; c < NCH; c++) {
    float2 v = Loc1[(size_t)(b * NCH + c) * 256 + d];
    h = v.x * h + v.y;
  }
  hlast[b * 256 + d] = h;
}

__global__ void cls_kernel(const float* __restrict__ hlast, const float* __restrict__ Wo,
                           const float* __restrict__ bo, float* __restrict__ out) {
  const int t = threadIdx.x;       // 256 = 32 b * 8 classes
  const int b = t >> 3, c = t & 7;
  float acc = bo[c];
  for (int d = 0; d < 256; d++) acc += hlast[b * 256 + d] * Wo[d * 8 + c];
  out[t] = acc;
}

extern "C" void kernel_launch(void* const* d_in, const int* in_sizes, int n_in,
                              void* d_out, int out_size, void* d_ws, size_t ws_size,
                              hipStream_t stream) {
  (void)in_sizes; (void)n_in; (void)out_size; (void)ws_size;
  const int*   x   = (const int*)d_in[0];
  const float* emb = (const float*)d_in[1];
  const float* Wz  = (const float*)d_in[2];
  const float* bz  = (const float*)d_in[3];
  const float* Wh  = (const float*)d_in[4];
  const float* bh  = (const float*)d_in[5];
  const float* Wo  = (const float*)d_in[6];
  const float* bo  = (const float*)d_in[7];
  float* out = (float*)d_out;
  char* ws = (char*)d_ws;

  // workspace layout (total ~33.3 MB; ws = 256 MiB)
  u16*    embq  = (u16*)   (ws);                      // 16,384,000 (pad to 16 MiB)
  u16*    WtS   = (u16*)   (ws + 16777216ull);        //    524,288
  u64*    Loc0  = (u64*)   (ws + 17301504ull);        //  8,388,608
  float2* Loc1  = (float2*)(ws + 25690112ull);        //  8,388,608
  float*  hlast = (float*) (ws + 34078720ull);        //     32,768
  int*    syncA = (int*)   (ws + 34111488ull);        //  (1+4096)*4

  embq_kernel<<<8000, 256, 0, stream>>>(emb, embq, syncA);
  wt_kernel<<<1024, 256, 0, stream>>>(Wz, Wh, WtS);

  fused_kernel<<<NBLK, 256, 0, stream>>>(
      x, embq, WtS, bz, bh, bz + 256, bh + 256,
      Loc0, Loc1, syncA + 1, syncA);

  scan2_l1<<<32, 256, 0, stream>>>(Loc1, hlast);
  cls_kernel<<<1, 256, 0, stream>>>(hlast, Wo, bo, out);
}

// Round 11
// 343.607 us; speedup vs baseline: 2.5684x; 2.5684x over previous
//
#include <hip/hip_runtime.h>
#include <stdint.h>

#define SEQ 8192
#define CS 64                       // chunk length == block row tile
#define NCH 128                     // chunks per sequence
#define NBLK 4096                   // 32 batches * 128 chunks

typedef float f32x4 __attribute__((ext_vector_type(4)));
typedef short short8 __attribute__((ext_vector_type(8)));
typedef unsigned short u16;
typedef u16 ushort8 __attribute__((ext_vector_type(8)));
typedef u16 ushort4v __attribute__((ext_vector_type(4)));

__device__ __forceinline__ u16 f2bf(float f) {
  uint32_t u = __float_as_uint(f);
  u += 0x7fffu + ((u >> 16) & 1u);   // round-to-nearest-even
  return (u16)(u >> 16);
}

// async 16B global->LDS (lds dest wave-uniform base; HW adds lane*16)
__device__ __forceinline__ void gld16(void* lds, const void* g) {
  __builtin_amdgcn_global_load_lds(
      (const __attribute__((address_space(1))) uint32_t*)g,
      (__attribute__((address_space(3))) uint32_t*)lds, 16, 0, 0);
}

// ---------- emb f32 -> bf16 table (one-time) ----------
__global__ void embq_kernel(const float* __restrict__ emb, u16* __restrict__ embq) {
  int i = (blockIdx.x * 256 + threadIdx.x) * 4;   // 8,192,000 elements exactly
  float4 v = *(const float4*)(emb + i);
  ushort4v p;
  p[0] = f2bf(v.x); p[1] = f2bf(v.y); p[2] = f2bf(v.z); p[3] = f2bf(v.w);
  *(ushort4v*)(embq + i) = p;
}

// ---------- weight preprocess: f32 [l][k][d] -> bf16 swizzled 8KB tiles ----------
// WtS: 64 tiles of 8192 BYTES, tile index (mat*4 + dh)*4 + kt, in-tile [64 dloc][64 kl],
// byte = (dloc*128 + kl*2) ^ ((dloc&7)<<4).  mat: 0=Wz l0,1=Wz l1,2=Wh l0,3=Wh l1
__global__ void wt_kernel(const float* __restrict__ Wz, const float* __restrict__ Wh,
                          u16* __restrict__ WtS) {
  int idx = blockIdx.x * 256 + threadIdx.x;   // 4*65536
  int d = idx & 255;
  int k = (idx >> 8) & 255;
  int m = idx >> 16;
  const float* src = (m < 2 ? Wz : Wh) + (size_t)(m & 1) * 65536;
  float v = src[k * 256 + d];
  int dh = d >> 6, dloc = d & 63, kt = k >> 6, kl = k & 63;
  size_t tile = ((size_t)(m * 4 + dh) * 4 + kt) * 8192;   // BYTES
  size_t byte = (size_t)((dloc * 128 + kl * 2) ^ ((dloc & 7) << 4));
  *(u16*)((char*)WtS + tile + byte) = f2bf(v);
}

// ---- stage one mat's kt B-tile (32KB: 4 dh-subtiles); wave w stages 4KB ----
__device__ __forceinline__ void stage_mat(char* Bbuf, const char* WtSb, int mat, int kt,
                                          int w, int lane) {
  const int dh = w >> 1, half = w & 1;
  const char* src = WtSb + ((size_t)((mat * 4 + dh) * 4 + kt)) * 8192 + half * 4096 + lane * 16;
  char* dst = Bbuf + dh * 8192 + half * 4096;
  #pragma unroll
  for (int i = 0; i < 4; i++)
    gld16(dst + i * 1024, src + i * 1024);
}

// ---- z/h-phased 4-kt MFMA core: A from LDS, one 32KB B buffer restaged per phase ----
__device__ __forceinline__ void core_zh(int lsel, const char* WtSb,
    const u16* As, char* Bbuf, int w, int wr, int wc, int l15, int lg, int lane,
    f32x4 (&accz)[2][4], f32x4 (&acch)[2][4])
{
  const int xm = (l15 & 7) << 4;
  for (int kt = 0; kt < 4; kt++) {
    __syncthreads();                         // Bbuf free (prev reads done)
    stage_mat(Bbuf, WtSb, lsel, kt, w, lane);          // Wz of this layer
    __syncthreads();                         // staged (drains vmcnt)
    short8 fa[2][2];
    #pragma unroll
    for (int ks = 0; ks < 2; ks++)
      #pragma unroll
      for (int mi = 0; mi < 2; mi++)
        fa[ks][mi] = *(const short8*)((const char*)As + kt * 8192 +
                       (((wr * 32 + mi * 16 + l15) * 128 + ks * 64 + lg * 16) ^ xm));
    #pragma unroll
    for (int ks = 0; ks < 2; ks++)
      #pragma unroll
      for (int ni = 0; ni < 4; ni++) {
        const int off = (((ni * 16 + l15) * 128 + ks * 64 + lg * 16) ^ xm);
        short8 fb = *(const short8*)(Bbuf + wc * 8192 + off);
        #pragma unroll
        for (int mi = 0; mi < 2; mi++)
          accz[mi][ni] = __builtin_amdgcn_mfma_f32_16x16x32_bf16(fa[ks][mi], fb, accz[mi][ni], 0, 0, 0);
      }
    __syncthreads();                         // z reads done
    stage_mat(Bbuf, WtSb, 2 + lsel, kt, w, lane);      // Wh of this layer
    __syncthreads();
    #pragma unroll
    for (int ks = 0; ks < 2; ks++)
      #pragma unroll
      for (int ni = 0; ni < 4; ni++) {
        const int off = (((ni * 16 + l15) * 128 + ks * 64 + lg * 16) ^ xm);
        short8 fb = *(const short8*)(Bbuf + wc * 8192 + off);
        #pragma unroll
        for (int mi = 0; mi < 2; mi++)
          acch[mi][ni] = __builtin_amdgcn_mfma_f32_16x16x32_bf16(fa[ks][mi], fb, acch[mi][ni], 0, 0, 0);
      }
  }
}

// SegT addressing (overlays As): seg row 2048B, XOR-swizzled by seg to spread banks
__device__ __forceinline__ float2* seg_ptr(char* segt, int s, int d) {
  return (float2*)(segt + s * 2048 + ((d * 8) ^ (s << 4)));
}

// ---------- unified GEMM kernel ----------
// Block: 512 threads (8 waves: wr=w>>2 rows, wc=w&3 cols), 64 rows x 256 d, K=256.
// PHASE 0: gemm0 -> chunk-local (A,B) totals -> Ap0/Bs0.  (no per-t output)
// PHASE 1: gemm0 recompute (a,b in regs) + carry -> rebuild h1 in LDS -> gemm1 -> Ap1/Bs1.
template<int PHASE>
__global__ __launch_bounds__(512, 4)
void gru_kernel(const int* __restrict__ x, const u16* __restrict__ embq,
                const u16* __restrict__ WtS,
                const float* __restrict__ bz0, const float* __restrict__ bh0,
                const float* __restrict__ bz1, const float* __restrict__ bh1,
                const float* __restrict__ carry,
                float* __restrict__ Ap, float* __restrict__ Bs)
{
  __shared__ __align__(16) u16 As[16384];    // 32KB: 4 kt-subtiles [64t][64k] swz; SegT overlay
  __shared__ __align__(16) char Bbuf[32768]; // 32KB: one mat's kt-tile (4 dh-subtiles)

  const int tid = threadIdx.x;
  const int lane = tid & 63;
  const int w = tid >> 6;
  const int wr = w >> 2, wc = w & 3;         // 2 row-groups x 4 col-groups
  const int l15 = lane & 15, lg = lane >> 4;
  const int cb = blockIdx.x;
  const int b = cb >> 7, c = cb & (NCH - 1);
  const char* WtSb = (const char*)WtS;
  char* segt = (char*)As;

  // ---- A gather: 64 rows x 256 k; thread = (row sm=tid>>3, 32-k chunk kq=tid&7) ----
  {
    const int sm = tid >> 3, kq = tid & 7;
    const int tok = x[b * SEQ + c * CS + sm];
    const u16* src = embq + (size_t)tok * 256 + kq * 32;
    char* sub = (char*)As + (kq >> 1) * 8192;
    const int kb = (kq & 1) * 64;
    const int swz = (sm & 7) << 4;
    #pragma unroll
    for (int j = 0; j < 4; j++) {
      ushort8 p = *(const ushort8*)(src + j * 8);
      *(ushort8*)(sub + ((sm * 128 + kb + j * 16) ^ swz)) = p;
    }
  }

  f32x4 accz[2][4], acch[2][4];
  #pragma unroll
  for (int i = 0; i < 2; i++)
    #pragma unroll
    for (int j = 0; j < 4; j++) {
      f32x4 zz = {0.f, 0.f, 0.f, 0.f};
      accz[i][j] = zz; acch[i][j] = zz;
    }

  __syncthreads();                           // As ready
  core_zh(0, WtSb, As, Bbuf, w, wr, wc, l15, lg, lane, accz, acch);
  __syncthreads();                           // all MFMA done; As free for SegT

  // ---- layer-0 gates -> SegT (PHASE1 keeps a,b in regs) ----
  #pragma unroll
  for (int ni = 0; ni < 4; ni++) {
    const int d = wc * 64 + ni * 16 + l15;
    const float bzv = bz0[d];
    const float bhv = bh0[d];
    #pragma unroll
    for (int mi = 0; mi < 2; mi++) {
      float A = 1.f, B = 0.f;
      #pragma unroll
      for (int r = 0; r < 4; r++) {
        float zl = accz[mi][ni][r] + bzv;
        float zg = 1.f / (1.f + __expf(-zl));
        float ht = acch[mi][ni][r] + bhv;
        float a = 1.f - zg, bb = zg * ht;
        if (PHASE == 1) { accz[mi][ni][r] = a; acch[mi][ni][r] = bb; }
        B = B * a + bb;
        A *= a;
      }
      *seg_ptr(segt, wr * 8 + mi * 4 + lg, d) = make_float2(A, B);
    }
  }
  __syncthreads();                           // SegT complete

  if (PHASE == 0) {
    // chunk totals -> Ap0/Bs0
    if (tid < 256) {
      float PA = 1.f, PB = 0.f;
      #pragma unroll
      for (int s = 0; s < 16; s++) {
        float2 v = *seg_ptr(segt, s, tid);
        PB = v.x * PB + v.y;
        PA *= v.x;
      }
      Ap[(size_t)cb * 256 + tid] = PA;
      Bs[(size_t)cb * 256 + tid] = PB;
    }
    return;
  }

  // ---- PHASE 1: exclusive prefix over 16 segs ----
  if (tid < 256) {
    float PA = 1.f, PB = 0.f;
    #pragma unroll
    for (int s = 0; s < 16; s++) {
      float2* p = seg_ptr(segt, s, tid);
      float2 v = *p;
      *p = make_float2(PA, PB);
      PB = v.x * PB + v.y;
      PA *= v.x;
    }
  }
  __syncthreads();                           // exclusive prefixes ready

  // ---- read own prefixes + carry; then rebuild h1 into As ----
  float ea[2][4], eb[2][4], h0v[4];
  #pragma unroll
  for (int ni = 0; ni < 4; ni++) {
    const int d = wc * 64 + ni * 16 + l15;
    h0v[ni] = carry[(size_t)cb * 256 + d];
    #pragma unroll
    for (int mi = 0; mi < 2; mi++) {
      float2 e = *seg_ptr(segt, wr * 8 + mi * 4 + lg, d);
      ea[mi][ni] = e.x; eb[mi][ni] = e.y;
    }
  }
  __syncthreads();                           // SegT reads done; As writable
  #pragma unroll
  for (int ni = 0; ni < 4; ni++) {
    const int d = wc * 64 + ni * 16 + l15;
    char* sub = (char*)As + (d >> 6) * 8192;
    const int kl2 = (d & 63) * 2;
    #pragma unroll
    for (int mi = 0; mi < 2; mi++) {
      float h = ea[mi][ni] * h0v[ni] + eb[mi][ni];
      #pragma unroll
      for (int r = 0; r < 4; r++) {
        h = accz[mi][ni][r] * h + acch[mi][ni][r];
        const int t = wr * 32 + mi * 16 + lg * 4 + r;
        *(u16*)(sub + ((t * 128 + kl2) ^ ((t & 7) << 4))) = f2bf(h);
      }
    }
  }

  #pragma unroll
  for (int i = 0; i < 2; i++)
    #pragma unroll
    for (int j = 0; j < 4; j++) {
      f32x4 zz = {0.f, 0.f, 0.f, 0.f};
      accz[i][j] = zz; acch[i][j] = zz;
    }

  core_zh(1, WtSb, As, Bbuf, w, wr, wc, l15, lg, lane, accz, acch);
  __syncthreads();                           // As free for SegT

  // ---- layer-1 gates -> SegT -> totals -> Ap1/Bs1 ----
  #pragma unroll
  for (int ni = 0; ni < 4; ni++) {
    const int d = wc * 64 + ni * 16 + l15;
    const float bzv = bz1[d];
    const float bhv = bh1[d];
    #pragma unroll
    for (int mi = 0; mi < 2; mi++) {
      float A = 1.f, B = 0.f;
      #pragma unroll
      for (int r = 0; r < 4; r++) {
        float zl = accz[mi][ni][r] + bzv;
        float zg = 1.f / (1.f + __expf(-zl));
        float ht = acch[mi][ni][r] + bhv;
        float a = 1.f - zg, bb = zg * ht;
        B = B * a + bb;
        A *= a;
      }
      *seg_ptr(segt, wr * 8 + mi * 4 + lg, d) = make_float2(A, B);
    }
  }
  __syncthreads();
  if (tid < 256) {
    float PA = 1.f, PB = 0.f;
    #pragma unroll
    for (int s = 0; s < 16; s++) {
      float2 v = *seg_ptr(segt, s, tid);
      PB = v.x * PB + v.y;
      PA *= v.x;
    }
    Ap[(size_t)cb * 256 + tid] = PA;
    Bs[(size_t)cb * 256 + tid] = PB;
  }
}

// ---------- serial cross-chunk compose: carry per chunk ----------
__global__ void scan2_l0(const float* __restrict__ Ap0, const float* __restrict__ Bs0,
                         float* __restrict__ carry) {
  const int g = blockIdx.x * 256 + threadIdx.x;   // 8192 = 32 b * 256 d
  const int b = g >> 8, d = g & 255;
  float h = 0.f;
  for (int c = 0; c < NCH; c++) {
    const size_t idx = (size_t)(b * NCH + c) * 256 + d;
    carry[idx] = h;
    h = Bs0[idx] + Ap0[idx] * h;
  }
}

// ---------- layer-1 final: serial over chunk locals -> hlast ----------
__global__ void scan2_l1(const float* __restrict__ Ap1, const float* __restrict__ Bs1,
                         float* __restrict__ hlast) {
  const int g = blockIdx.x * 256 + threadIdx.x;   // 8192
  const int b = g >> 8, d = g & 255;
  float h = 0.f;
  for (int c = 0; c < NCH; c++) {
    const size_t idx = (size_t)(b * NCH + c) * 256 + d;
    h = Bs1[idx] + Ap1[idx] * h;
  }
  hlast[b * 256 + d] = h;
}

__global__ void cls_kernel(const float* __restrict__ hlast, const float* __restrict__ Wo,
                           const float* __restrict__ bo, float* __restrict__ out) {
  const int t = threadIdx.x;       // 256 = 32 b * 8 classes
  const int b = t >> 3, c = t & 7;
  float acc = bo[c];
  for (int d = 0; d < 256; d++) acc += hlast[b * 256 + d] * Wo[d * 8 + c];
  out[t] = acc;
}

extern "C" void kernel_launch(void* const* d_in, const int* in_sizes, int n_in,
                              void* d_out, int out_size, void* d_ws, size_t ws_size,
                              hipStream_t stream) {
  (void)in_sizes; (void)n_in; (void)out_size; (void)ws_size;
  const int*   x   = (const int*)d_in[0];
  const float* emb = (const float*)d_in[1];
  const float* Wz  = (const float*)d_in[2];
  const float* bz  = (const float*)d_in[3];
  const float* Wh  = (const float*)d_in[4];
  const float* bh  = (const float*)d_in[5];
  const float* Wo  = (const float*)d_in[6];
  const float* bo  = (const float*)d_in[7];
  float* out = (float*)d_out;
  char* ws = (char*)d_ws;

  // workspace (~38.3 MB; ws = 256 MiB)
  u16*   embq  = (u16*)  (ws);                      // 16,384,000 (pad to 16 MiB)
  u16*   WtS   = (u16*)  (ws + 16777216ull);        //    524,288
  float* Ap0   = (float*)(ws + 17301504ull);        //  4,194,304
  float* Bs0   = (float*)(ws + 21495808ull);        //  4,194,304
  float* carry = (float*)(ws + 25690112ull);        //  4,194,304
  float* Ap1   = (float*)(ws + 29884416ull);        //  4,194,304
  float* Bs1   = (float*)(ws + 34078720ull);        //  4,194,304
  float* hlast = (float*)(ws + 38273024ull);        //     32,768

  embq_kernel<<<8000, 256, 0, stream>>>(emb, embq);
  wt_kernel<<<1024, 256, 0, stream>>>(Wz, Wh, WtS);

  gru_kernel<0><<<NBLK, 512, 0, stream>>>(
      x, embq, WtS, bz, bh, bz + 256, bh + 256, nullptr, Ap0, Bs0);
  scan2_l0<<<32, 256, 0, stream>>>(Ap0, Bs0, carry);
  gru_kernel<1><<<NBLK, 512, 0, stream>>>(
      x, embq, WtS, bz, bh, bz + 256, bh + 256, carry, Ap1, Bs1);

  scan2_l1<<<32, 256, 0, stream>>>(Ap1, Bs1, hlast);
  cls_kernel<<<1, 256, 0, stream>>>(hlast, Wo, bo, out);
}